// Round 7
// baseline (102.154 us; speedup 1.0000x reference)
//
#include <hip/hip_runtime.h>
#include <hip/hip_bf16.h>

typedef __attribute__((ext_vector_type(8))) short bf16x8;
typedef __attribute__((ext_vector_type(4))) float f32x4;

#define NB 4096
#define ND 512
#define MARGIN_F 0.2f

// order-preserving float -> uint encoding for atomicMax.
__device__ __forceinline__ unsigned int enc_f32(float f) {
    unsigned int b = __float_as_uint(f);
    return (b & 0x80000000u) ? ~b : (b | 0x80000000u);
}

__device__ __forceinline__ float dec_f32(unsigned int e) {
    unsigned int b = (e & 0x80000000u) ? (e & 0x7fffffffu) : ~e;
    return __uint_as_float(b);
}

__device__ __forceinline__ void gld_lds16(const void* g, void* l) {
    __builtin_amdgcn_global_load_lds((__attribute__((address_space(1))) void*)g,
                                     (__attribute__((address_space(3))) void*)l,
                                     16, 0, 0);
}

// branchless dynamic element select from f32x4 (constant extracts + cndmask)
__device__ __forceinline__ float selv(f32x4 v, int r) {
    float s01 = (r & 1) ? v[1] : v[0];
    float s23 = (r & 1) ? v[3] : v[2];
    return (r & 2) ? s23 : s01;
}

// ---------------------------------------------------------------------------
// Prep: fp32 -> bf16 fragment-swizzled convert (both matrices), grid 2048.
// Blocks [0,16) additionally zero the 4096-entry rowmax array.
// Layout: chunk (rb16 = row/16, cb = col/32) is 1KB at (rb16*16+cb)*1024;
// within chunk lane L = (row%16) | (((col%32)/8)<<4) holds 8 bf16 at L*16.
// ---------------------------------------------------------------------------
__global__ __launch_bounds__(256) void k_prep(const float* __restrict__ zs,
                                              const float* __restrict__ zi,
                                              __hip_bfloat16* __restrict__ outb,
                                              unsigned int* __restrict__ rowmax) {
    const int bid = blockIdx.x;
    if (bid < 16) rowmax[bid * 256 + threadIdx.x] = 0u;

    int gid = bid * 256 + threadIdx.x;   // [0, 2*4096*64)
    int mat = gid >> 18;                 // 0 = zs, 1 = zi
    int t   = gid & 0x3FFFF;
    int si  = t >> 6;
    int L   = t & 63;
    const float* src = mat ? zi : zs;
    int row = ((si >> 4) << 4) | (L & 15);
    int col = ((si & 15) << 5) | (((L >> 4) & 3) << 3);
    const float4* p = (const float4*)(src + (size_t)row * ND + col);
    float4 f0 = p[0];
    float4 f1 = p[1];
    union { __hip_bfloat16 h[8]; bf16x8 v; } u;
    u.h[0] = __float2bfloat16(f0.x);
    u.h[1] = __float2bfloat16(f0.y);
    u.h[2] = __float2bfloat16(f0.z);
    u.h[3] = __float2bfloat16(f0.w);
    u.h[4] = __float2bfloat16(f1.x);
    u.h[5] = __float2bfloat16(f1.y);
    u.h[6] = __float2bfloat16(f1.z);
    u.h[7] = __float2bfloat16(f1.w);
    bf16x8* dst = (bf16x8*)(outb + ((size_t)mat << 21) + ((size_t)si << 9) + (L << 3));
    *dst = u.v;
}

// ---------------------------------------------------------------------------
// 128x128 tile GEMM (S = Zs . Zi^T), BK=64, 4 waves (2M x 2N), wave tile
// 64x64 = 4x4 of 16x16x32 bf16 MFMA, 16 named f32x4 accumulators.
//
// ROUND 7 RATIONALE: R3/R4/R6 (three different 256-tile 8-wave schedules)
// were all ~33-45 us -- schedule-invariant, all pipes idle (R5: Mfma 9%,
// VALU 7%, HBM 3%), 1 block/CU barrier-lockstep with K=512 too shallow to
// reach steady state. This is the m97/m103 config instead: 64 KB LDS
// double-buffer -> 2 blocks/CU resident (grid 1024 = 4/CU queued), plain
// 2-phase loop, compiler scheduling. Cross-BLOCK overlap hides the barrier
// drain (m114: implicit wave-level overlap at 2-3 blocks/CU captures what
// source-level pipelining would add; m97/m103: 874-912 TF verified).
//
// LDS: A buf = 2 x 16 KB at 0, B buf = 2 x 16 KB at 32768. Tile parity
// par = (kt&1)*16384. Chunk c = rb16local*2 + q (q = k-half) is 1 KB at
// c*1024; within chunk lane L holds row (L&15), cols q*32 + ((L>>4)&3)*8
// (fragment-major: ds_read_b128 and gld_lds writes both conflict-free).
// ---------------------------------------------------------------------------
__global__ __launch_bounds__(256, 2) void k_gemm_rowmax(const __hip_bfloat16* __restrict__ zsb,
                                                        const __hip_bfloat16* __restrict__ zib,
                                                        const int* __restrict__ labels,
                                                        unsigned int* __restrict__ rowmax,
                                                        float* __restrict__ p_diag) {
    __shared__ __align__(16) unsigned char lds[65536];
    __shared__ int labA[128];
    __shared__ int labB[128];

    const int tid = threadIdx.x;
    // Bijective XCD swizzle (grid 1024, 1024%8==0): xcd = bid&7 owns a
    // 16(bx) x 8(by) tile region -> A 1 MB + B 2 MB = 3 MB < 4 MB L2/XCD.
    const int bid = blockIdx.x;
    const int xcd = bid & 7, lid = bid >> 3;       // lid in [0,128)
    const int bx = ((xcd & 1) << 4) | (lid & 15);  // [0,32)
    const int by = ((xcd >> 1) << 3) | (lid >> 4); // [0,32)

    if (tid < 128) labA[tid] = labels[by * 128 + tid];
    else           labB[tid - 128] = labels[bx * 128 + (tid - 128)];

    const char* gA = (const char*)zsb;
    const char* gB = (const char*)zib;
    const int rbw = tid >> 6;            // wave index 0..3
    const int cw  = (tid & 63) << 4;     // lane*16 within 1 KB chunk
    const int q_t = rbw & 1;             // this thread's staged k-half
    const int rb_t = rbw >> 1;           // rb16 sub-offset 0/1
    const int aQ = by * 8;               // A rb16 base (global)
    const int bQ = bx * 8;               // B rb16 base (global)

    // STAGE(kt): stage full 32 KB tile (A 16 KB + B 16 KB), 8 loads/thread.
    // Chunk c = j*4 + rbw -> rb16local = j*2 + rb_t, k-half = q_t.
    // Global src: (rb16global<<14) + (kt*2 + q_t)*1024 + lane*16.
    // LDS dest:   region + par + c*1024 + lane*16 = region + par + tid*16 + j*4096.
#define STAGE(kt) do {                                                             \
        size_t _gc = ((size_t)(((kt) << 1) + q_t) << 10) + cw;                     \
        unsigned _ld = (((kt) & 1) << 14) + (tid << 4);                            \
        gld_lds16(gA + (((size_t)(aQ + 0 + rb_t)) << 14) + _gc, lds + _ld);        \
        gld_lds16(gA + (((size_t)(aQ + 2 + rb_t)) << 14) + _gc, lds + _ld + 4096); \
        gld_lds16(gA + (((size_t)(aQ + 4 + rb_t)) << 14) + _gc, lds + _ld + 8192); \
        gld_lds16(gA + (((size_t)(aQ + 6 + rb_t)) << 14) + _gc, lds + _ld + 12288);\
        gld_lds16(gB + (((size_t)(bQ + 0 + rb_t)) << 14) + _gc, lds + 32768 + _ld);\
        gld_lds16(gB + (((size_t)(bQ + 2 + rb_t)) << 14) + _gc, lds + 32768 + _ld + 4096); \
        gld_lds16(gB + (((size_t)(bQ + 4 + rb_t)) << 14) + _gc, lds + 32768 + _ld + 8192); \
        gld_lds16(gB + (((size_t)(bQ + 6 + rb_t)) << 14) + _gc, lds + 32768 + _ld + 12288);\
    } while (0)

    const int w = tid >> 6, lane = tid & 63;
    const int w_m = w >> 1, w_n = w & 1;
    const unsigned fragOff = (unsigned)(lane << 4);
    // frag (rb16local = w_m*4 + ms, q): byte = (w_m*4+ms)*2048 + q*1024 + fragOff
    const unsigned aBase = (unsigned)(w_m << 13) + fragOff;
    const unsigned bBase = 32768u + (unsigned)(w_n << 13) + fragOff;

    const f32x4 Z4 = (f32x4){0.f, 0.f, 0.f, 0.f};
    f32x4 acc00=Z4, acc01=Z4, acc02=Z4, acc03=Z4;
    f32x4 acc10=Z4, acc11=Z4, acc12=Z4, acc13=Z4;
    f32x4 acc20=Z4, acc21=Z4, acc22=Z4, acc23=Z4;
    f32x4 acc30=Z4, acc31=Z4, acc32=Z4, acc33=Z4;
    bf16x8 a_0, a_1, a_2, a_3, b_0, b_1, b_2, b_3;

#define MF(A, B, C) __builtin_amdgcn_mfma_f32_16x16x32_bf16((A), (B), (C), 0, 0, 0)
#define LDBq(q)                                                                \
    b_0 = *(const bf16x8*)(lds + par + bBase + 0 * 2048 + ((q) << 10));        \
    b_1 = *(const bf16x8*)(lds + par + bBase + 1 * 2048 + ((q) << 10));        \
    b_2 = *(const bf16x8*)(lds + par + bBase + 2 * 2048 + ((q) << 10));        \
    b_3 = *(const bf16x8*)(lds + par + bBase + 3 * 2048 + ((q) << 10));
#define LDAq(q)                                                                \
    a_0 = *(const bf16x8*)(lds + par + aBase + 0 * 2048 + ((q) << 10));        \
    a_1 = *(const bf16x8*)(lds + par + aBase + 1 * 2048 + ((q) << 10));        \
    a_2 = *(const bf16x8*)(lds + par + aBase + 2 * 2048 + ((q) << 10));        \
    a_3 = *(const bf16x8*)(lds + par + aBase + 3 * 2048 + ((q) << 10));
#define ROW4(A, R)                                                             \
    acc##R##0 = MF((A), b_0, acc##R##0);                                       \
    acc##R##1 = MF((A), b_1, acc##R##1);                                       \
    acc##R##2 = MF((A), b_2, acc##R##2);                                       \
    acc##R##3 = MF((A), b_3, acc##R##3);

    // prologue: tile 0 staged; __syncthreads drains vmcnt + publishes labs
    STAGE(0);
    __syncthreads();

#pragma unroll
    for (int kt = 0; kt < 8; ++kt) {
        const unsigned par = (unsigned)((kt & 1) << 14);
        if (kt < 7) STAGE(kt + 1);           // issue next tile first (T3-min)
        LDBq(0)
        LDAq(0)
        ROW4(a_0, 0) ROW4(a_1, 1) ROW4(a_2, 2) ROW4(a_3, 3)
        LDBq(1)
        LDAq(1)
        ROW4(a_0, 0) ROW4(a_1, 1) ROW4(a_2, 2) ROW4(a_3, 3)
        if (kt < 7) __syncthreads();         // drains vm+lgkm; next tile ready
    }
#undef STAGE
#undef LDAq
#undef LDBq
#undef ROW4

    // epilogue: C/D layout col = lane&15, row = (lane>>4)*4 + reg
    const int quad = lane >> 4;
    const int lcol = lane & 15;
    const int epiBase = by * 128 + w_m * 64 + quad * 4;

    const int lb_0 = labB[w_n * 64 + 0 * 16 + lcol];
    const int lb_1 = labB[w_n * 64 + 1 * 16 + lcol];
    const int lb_2 = labB[w_n * 64 + 2 * 16 + lcol];
    const int lb_3 = labB[w_n * 64 + 3 * 16 + lcol];

#define EPIV(m, n, LB) {                                                       \
        float v0 = acc##m##n[0], v1 = acc##m##n[1];                            \
        float v2 = acc##m##n[2], v3 = acc##m##n[3];                            \
        if (la0 != (LB) && v0 > mx0) mx0 = v0;                                 \
        if (la1 != (LB) && v1 > mx1) mx1 = v1;                                 \
        if (la2 != (LB) && v2 > mx2) mx2 = v2;                                 \
        if (la3 != (LB) && v3 > mx3) mx3 = v3; }
#define EPIRED(m, r, MX) {                                                     \
        float mm = (MX);                                                       \
        mm = fmaxf(mm, __shfl_xor(mm, 1));                                     \
        mm = fmaxf(mm, __shfl_xor(mm, 2));                                     \
        mm = fmaxf(mm, __shfl_xor(mm, 4));                                     \
        mm = fmaxf(mm, __shfl_xor(mm, 8));                                     \
        if (lcol == 0 && mm > -2.9e38f)                                        \
            atomicMax(&rowmax[epiBase + (m) * 16 + (r)], enc_f32(mm)); }
#define EPIMS(m) {                                                             \
        int la0 = labA[w_m * 64 + (m) * 16 + quad * 4 + 0];                    \
        int la1 = labA[w_m * 64 + (m) * 16 + quad * 4 + 1];                    \
        int la2 = labA[w_m * 64 + (m) * 16 + quad * 4 + 2];                    \
        int la3 = labA[w_m * 64 + (m) * 16 + quad * 4 + 3];                    \
        float mx0 = -3.0e38f, mx1 = -3.0e38f, mx2 = -3.0e38f, mx3 = -3.0e38f;  \
        EPIV(m, 0, lb_0) EPIV(m, 1, lb_1) EPIV(m, 2, lb_2) EPIV(m, 3, lb_3)    \
        EPIRED(m, 0, mx0) EPIRED(m, 1, mx1) EPIRED(m, 2, mx2) EPIRED(m, 3, mx3) }

    EPIMS(0) EPIMS(1) EPIMS(2) EPIMS(3)
#undef EPIMS
#undef EPIRED
#undef EPIV

    // diagonal blocks: p[a] = 1 - S[a][a]. Wave covers the diagonal iff
    // w_m == w_n; diag frags are ms == ns, frag-row lcol, element r =
    // lcol&3 (valid iff quad == lcol>>2). All-constant indexing.
    if (bx == by && w_m == w_n && (lcol >> 2) == quad) {
        int r = lcol & 3;
        int base = by * 128 + w_m * 64 + lcol;
        p_diag[base +  0] = 1.0f - selv(acc00, r);
        p_diag[base + 16] = 1.0f - selv(acc11, r);
        p_diag[base + 32] = 1.0f - selv(acc22, r);
        p_diag[base + 48] = 1.0f - selv(acc33, r);
    }
}

// ---------------------------------------------------------------------------
// Finalize: has_neg = (rowmax != 0); n = 1 - dec(rowmax);
// per = relu(p - n + margin); masked mean -> out[0]
// ---------------------------------------------------------------------------
__global__ __launch_bounds__(1024) void k_finalize(const unsigned int* __restrict__ rowmax,
                                                   const float* __restrict__ p_diag,
                                                   float* __restrict__ out) {
    int tid = threadIdx.x;
    float sum = 0.0f;
    int cnt = 0;
#pragma unroll
    for (int it = 0; it < 4; ++it) {
        int a = tid + it * 1024;
        unsigned int e = rowmax[a];
        if (e != 0u) {
            float n = 1.0f - dec_f32(e);
            float per = p_diag[a] - n + MARGIN_F;
            if (per > 0.0f) sum += per;
            cnt++;
        }
    }
#pragma unroll
    for (int off = 32; off > 0; off >>= 1) {
        sum += __shfl_xor(sum, off);
        cnt += __shfl_xor(cnt, off);
    }
    __shared__ float sSum[16];
    __shared__ int sCnt[16];
    int w = tid >> 6, lane = tid & 63;
    if (lane == 0) { sSum[w] = sum; sCnt[w] = cnt; }
    __syncthreads();
    if (tid == 0) {
        float ts = 0.0f;
        int tc = 0;
#pragma unroll
        for (int i = 0; i < 16; ++i) { ts += sSum[i]; tc += sCnt[i]; }
        out[0] = (tc > 0) ? ts / (float)tc : 0.0f;
    }
}

extern "C" void kernel_launch(void* const* d_in, const int* in_sizes, int n_in,
                              void* d_out, int out_size, void* d_ws, size_t ws_size,
                              hipStream_t stream) {
    (void)in_sizes; (void)n_in; (void)out_size; (void)ws_size;
    const float* zs = (const float*)d_in[0];
    const float* zi = (const float*)d_in[1];
    const int* labels = (const int*)d_in[2];
    float* out = (float*)d_out;

    char* ws = (char*)d_ws;
    __hip_bfloat16* zb = (__hip_bfloat16*)ws;                       // 8 MB (zs then zi, swizzled)
    unsigned int* rowmax = (unsigned int*)(ws + (8u << 20));        // 16 KB
    float* p_diag = (float*)(ws + (8u << 20) + 16384);              // 16 KB

    k_prep<<<2048, 256, 0, stream>>>(zs, zi, zb, rowmax);
    k_gemm_rowmax<<<1024, 256, 0, stream>>>(zb, zb + (size_t)NB * ND, labels, rowmax, p_diag);
    k_finalize<<<1, 1024, 0, stream>>>(rowmax, p_diag, out);
}

// Round 8
// 100.663 us; speedup vs baseline: 1.0148x; 1.0148x over previous
//
#include <hip/hip_runtime.h>
#include <hip/hip_bf16.h>

typedef __attribute__((ext_vector_type(8))) short bf16x8;
typedef __attribute__((ext_vector_type(4))) float f32x4;

#define NB 4096
#define ND 512
#define MARGIN_F 0.2f

// order-preserving float -> uint encoding for atomicMax.
__device__ __forceinline__ unsigned int enc_f32(float f) {
    unsigned int b = __float_as_uint(f);
    return (b & 0x80000000u) ? ~b : (b | 0x80000000u);
}

__device__ __forceinline__ float dec_f32(unsigned int e) {
    unsigned int b = (e & 0x80000000u) ? (e & 0x7fffffffu) : ~e;
    return __uint_as_float(b);
}

__device__ __forceinline__ void gld_lds16(const void* g, void* l) {
    __builtin_amdgcn_global_load_lds((__attribute__((address_space(1))) void*)g,
                                     (__attribute__((address_space(3))) void*)l,
                                     16, 0, 0);
}

// branchless dynamic element select from f32x4 (constant extracts + cndmask)
__device__ __forceinline__ float selv(f32x4 v, int r) {
    float s01 = (r & 1) ? v[1] : v[0];
    float s23 = (r & 1) ? v[3] : v[2];
    return (r & 2) ? s23 : s01;
}

// ---------------------------------------------------------------------------
// Prep: fp32 -> bf16 fragment-swizzled convert (both matrices), grid 2048.
// Blocks [0,16) additionally zero the 4096-entry rowmax array; block 16
// zeroes the last-block-done counter (workspace is poisoned per-iteration).
// Layout: chunk (rb16 = row/16, cb = col/32) is 1KB at (rb16*16+cb)*1024;
// within chunk lane L = (row%16) | (((col%32)/8)<<4) holds 8 bf16 at L*16.
// ---------------------------------------------------------------------------
__global__ __launch_bounds__(256) void k_prep(const float* __restrict__ zs,
                                              const float* __restrict__ zi,
                                              __hip_bfloat16* __restrict__ outb,
                                              unsigned int* __restrict__ rowmax,
                                              unsigned int* __restrict__ doneCnt) {
    const int bid = blockIdx.x;
    if (bid < 16) rowmax[bid * 256 + threadIdx.x] = 0u;
    if (bid == 16 && threadIdx.x == 0) *doneCnt = 0u;

    int gid = bid * 256 + threadIdx.x;   // [0, 2*4096*64)
    int mat = gid >> 18;                 // 0 = zs, 1 = zi
    int t   = gid & 0x3FFFF;
    int si  = t >> 6;
    int L   = t & 63;
    const float* src = mat ? zi : zs;
    int row = ((si >> 4) << 4) | (L & 15);
    int col = ((si & 15) << 5) | (((L >> 4) & 3) << 3);
    const float4* p = (const float4*)(src + (size_t)row * ND + col);
    float4 f0 = p[0];
    float4 f1 = p[1];
    union { __hip_bfloat16 h[8]; bf16x8 v; } u;
    u.h[0] = __float2bfloat16(f0.x);
    u.h[1] = __float2bfloat16(f0.y);
    u.h[2] = __float2bfloat16(f0.z);
    u.h[3] = __float2bfloat16(f0.w);
    u.h[4] = __float2bfloat16(f1.x);
    u.h[5] = __float2bfloat16(f1.y);
    u.h[6] = __float2bfloat16(f1.z);
    u.h[7] = __float2bfloat16(f1.w);
    bf16x8* dst = (bf16x8*)(outb + ((size_t)mat << 21) + ((size_t)si << 9) + (L << 3));
    *dst = u.v;
}

// ---------------------------------------------------------------------------
// 256x256 tile GEMM (S = Zs . Zi^T), BK=64, 8 waves (2M x 4N), wave tile
// 128x64. K-loop byte-identical to round 4 (best total, 97.8 us; four
// schedule variants R3/R4/R6/R7 all within 2% => schedule exhausted at this
// shape; m102 equal-FLOP reference = 320 TF, we are at ~500+).
//
// NEW (round 8): FENCE-FREE fused finalize. R5's fused version cost +21 us
// with per-block __threadfence() (device release => L2-writeback class on
// multi-XCD). Here ALL cross-block communication is device-scope atomic
// RMWs only (coherence-point ops, no fence needed):
//   - rowmax: atomicMax (already was)
//   - p_diag: atomicExch on float bits
//   - signal: s_waitcnt vmcnt(0) (all prior atomics ACKed) + barrier, then
//     tid0 atomicAdd(doneCnt); last block (old==255) reduces, reading
//     rowmax/p_diag via atomicOr(p,0) RMW-reads at the coherence point.
// ---------------------------------------------------------------------------
__global__ __launch_bounds__(512, 2) void k_gemm_rowmax(const __hip_bfloat16* __restrict__ zsb,
                                                        const __hip_bfloat16* __restrict__ zib,
                                                        const int* __restrict__ labels,
                                                        unsigned int* __restrict__ rowmax,
                                                        unsigned int* __restrict__ p_diag_u,
                                                        unsigned int* __restrict__ doneCnt,
                                                        float* __restrict__ out) {
    __shared__ __align__(16) unsigned char lds[131072];
    __shared__ int labA[256];
    __shared__ int labB[256];

    const int tid = threadIdx.x;
    // XCD-aware swizzle: each XCD (bid&7) owns a 4(bx) x 8(by) tile region
    // -> working set 4 B-panels + 8 A-panels = 3 MB < 4 MB per-XCD L2.
    const int bid = blockIdx.x;
    const int xcd = bid & 7, lid = bid >> 3;
    const int bx = ((xcd & 3) << 2) | (lid & 3);
    const int by = ((xcd >> 2) << 3) | (lid >> 2);

    if (tid < 256) labA[tid] = labels[by * 256 + tid];
    else           labB[tid & 255] = labels[bx * 256 + (tid & 255)];

    const char* gA = (const char*)zsb;
    const char* gB = (const char*)zib;
    const int inner = (tid & 127) << 4;        // byte offset within 2KB (rb, kt) strip
    const int aB16 = by * 16 + (tid >> 7);     // staging row-block base (A)
    const int bB16 = bx * 16 + (tid >> 7);     // staging row-block base (B)

    // STAGE(kt, h): 2 x 16B per thread into half-tile slot h of buf[kt&1].
#define STAGE(kt, h) do {                                                          \
        const char* _g = ((h) & 2) ? gB : gA;                                      \
        int _rb = (((h) & 2) ? bB16 : aB16) + (((h) & 1) << 3);                    \
        unsigned _ld = (((kt) & 1) << 16) + ((h) << 14) + (tid << 4);              \
        gld_lds16(_g + (((size_t)_rb) << 14) + ((kt) << 11) + inner, lds + _ld);   \
        gld_lds16(_g + (((size_t)(_rb + 4)) << 14) + ((kt) << 11) + inner,         \
                  lds + _ld + 8192);                                               \
    } while (0)

    const int w = tid >> 6, lane = tid & 63;
    const int w_m = w >> 2, w_n = w & 3;
    const unsigned fragOff = (unsigned)(lane << 4);
    const unsigned aBase = (unsigned)(w_m << 14) + fragOff;
    const unsigned bBase = 32768u + (unsigned)((w_n >> 1) << 14)
                         + (unsigned)(((w_n & 1) << 2) << 11) + fragOff;

    const f32x4 Z4 = (f32x4){0.f, 0.f, 0.f, 0.f};
    f32x4 acc00=Z4, acc01=Z4, acc02=Z4, acc03=Z4;
    f32x4 acc10=Z4, acc11=Z4, acc12=Z4, acc13=Z4;
    f32x4 acc20=Z4, acc21=Z4, acc22=Z4, acc23=Z4;
    f32x4 acc30=Z4, acc31=Z4, acc32=Z4, acc33=Z4;
    f32x4 acc40=Z4, acc41=Z4, acc42=Z4, acc43=Z4;
    f32x4 acc50=Z4, acc51=Z4, acc52=Z4, acc53=Z4;
    f32x4 acc60=Z4, acc61=Z4, acc62=Z4, acc63=Z4;
    f32x4 acc70=Z4, acc71=Z4, acc72=Z4, acc73=Z4;
    bf16x8 a_0, a_1, a_2, a_3, b_0, b_1, b_2, b_3;

#define MF(A, B, C) __builtin_amdgcn_mfma_f32_16x16x32_bf16((A), (B), (C), 0, 0, 0)
#define LDB(koff)                                                              \
    b_0 = *(const bf16x8*)(lds + par + bBase + (0 << 11) + (koff));            \
    b_1 = *(const bf16x8*)(lds + par + bBase + (1 << 11) + (koff));            \
    b_2 = *(const bf16x8*)(lds + par + bBase + (2 << 11) + (koff));            \
    b_3 = *(const bf16x8*)(lds + par + bBase + (3 << 11) + (koff));
#define LDA(mh, koff)                                                          \
    a_0 = *(const bf16x8*)(lds + par + aBase + ((((mh) << 2) + 0) << 11) + (koff)); \
    a_1 = *(const bf16x8*)(lds + par + aBase + ((((mh) << 2) + 1) << 11) + (koff)); \
    a_2 = *(const bf16x8*)(lds + par + aBase + ((((mh) << 2) + 2) << 11) + (koff)); \
    a_3 = *(const bf16x8*)(lds + par + aBase + ((((mh) << 2) + 3) << 11) + (koff));
#define ROW4(A, R)                                                             \
    acc##R##0 = MF((A), b_0, acc##R##0);                                       \
    acc##R##1 = MF((A), b_1, acc##R##1);                                       \
    acc##R##2 = MF((A), b_2, acc##R##2);                                       \
    acc##R##3 = MF((A), b_3, acc##R##3);
    // m201 phase discipline: barrier -> drain lgkm -> pin order -> prio MFMA
#define PHASE_SYNC()                                                           \
    __builtin_amdgcn_s_barrier();                                              \
    asm volatile("s_waitcnt lgkmcnt(0)" ::: "memory");                         \
    __builtin_amdgcn_sched_barrier(0);

    // prologue: T0 fully + T1's B halves, then one full drain
    STAGE(0, 0); STAGE(0, 1); STAGE(0, 2); STAGE(0, 3);
    STAGE(1, 2); STAGE(1, 3);
    __syncthreads();

#pragma unroll
    for (int kt = 0; kt < 8; ++kt) {
        const unsigned par = (unsigned)((kt & 1) << 16);

        // ---- P0: b0(k0) + a(mh0,k0); stage T(kt+1).h0; MFMA rows 0..3 ----
        LDB(0)
        LDA(0, 0)
        if (kt < 7) STAGE(kt + 1, 0);
        PHASE_SYNC()
        __builtin_amdgcn_s_setprio(1);
        ROW4(a_0, 0) ROW4(a_1, 1) ROW4(a_2, 2) ROW4(a_3, 3)
        __builtin_amdgcn_s_setprio(0);
        __builtin_amdgcn_s_barrier();

        // ---- P1: a(mh1,k0); stage T(kt+1).h1; MFMA rows 4..7 ----
        LDA(1, 0)
        if (kt < 7) STAGE(kt + 1, 1);
        PHASE_SYNC()
        __builtin_amdgcn_s_setprio(1);
        ROW4(a_0, 4) ROW4(a_1, 5) ROW4(a_2, 6) ROW4(a_3, 7)
        __builtin_amdgcn_s_setprio(0);
        __builtin_amdgcn_s_barrier();

        // ---- P2: b1(k1) + a(mh0,k1); MFMA rows 0..3 ----
        LDB(1024)
        LDA(0, 1024)
        PHASE_SYNC()
        __builtin_amdgcn_s_setprio(1);
        ROW4(a_0, 0) ROW4(a_1, 1) ROW4(a_2, 2) ROW4(a_3, 3)
        __builtin_amdgcn_s_setprio(0);
        __builtin_amdgcn_s_barrier();

        // ---- P3: a(mh1,k1); stage T(kt+2).h2,h3; MFMA rows 4..7; boundary ----
        LDA(1, 1024)
        if (kt < 6) { STAGE(kt + 2, 2); STAGE(kt + 2, 3); }
        PHASE_SYNC()
        __builtin_amdgcn_s_setprio(1);
        ROW4(a_0, 4) ROW4(a_1, 5) ROW4(a_2, 6) ROW4(a_3, 7)
        __builtin_amdgcn_s_setprio(0);
        if (kt < 6) {
            asm volatile("s_waitcnt vmcnt(4)" ::: "memory");   // all of T(kt+1) landed
            __builtin_amdgcn_s_barrier();
        } else if (kt == 6) {
            asm volatile("s_waitcnt vmcnt(0)" ::: "memory");   // tail: T7 fully landed
            __builtin_amdgcn_s_barrier();
        }
    }
#undef STAGE
#undef LDA
#undef LDB
#undef ROW4
#undef PHASE_SYNC

    // epilogue: C/D layout col = lane&15, row = (lane>>4)*4 + reg
    const int quad = lane >> 4;
    const int lcol = lane & 15;
    const int epiBase = by * 256 + w_m * 128 + quad * 4;

    const int lb_0 = labB[w_n * 64 + 0 * 16 + lcol];
    const int lb_1 = labB[w_n * 64 + 1 * 16 + lcol];
    const int lb_2 = labB[w_n * 64 + 2 * 16 + lcol];
    const int lb_3 = labB[w_n * 64 + 3 * 16 + lcol];

#define EPIV(m, n, LB) {                                                       \
        float v0 = acc##m##n[0], v1 = acc##m##n[1];                            \
        float v2 = acc##m##n[2], v3 = acc##m##n[3];                            \
        if (la0 != (LB) && v0 > mx0) mx0 = v0;                                 \
        if (la1 != (LB) && v1 > mx1) mx1 = v1;                                 \
        if (la2 != (LB) && v2 > mx2) mx2 = v2;                                 \
        if (la3 != (LB) && v3 > mx3) mx3 = v3; }
#define EPIRED(m, r, MX) {                                                     \
        float mm = (MX);                                                       \
        mm = fmaxf(mm, __shfl_xor(mm, 1));                                     \
        mm = fmaxf(mm, __shfl_xor(mm, 2));                                     \
        mm = fmaxf(mm, __shfl_xor(mm, 4));                                     \
        mm = fmaxf(mm, __shfl_xor(mm, 8));                                     \
        if (lcol == 0 && mm > -2.9e38f)                                        \
            atomicMax(&rowmax[epiBase + (m) * 16 + (r)], enc_f32(mm)); }
#define EPIMS(m) {                                                             \
        int la0 = labA[w_m * 128 + (m) * 16 + quad * 4 + 0];                   \
        int la1 = labA[w_m * 128 + (m) * 16 + quad * 4 + 1];                   \
        int la2 = labA[w_m * 128 + (m) * 16 + quad * 4 + 2];                   \
        int la3 = labA[w_m * 128 + (m) * 16 + quad * 4 + 3];                   \
        float mx0 = -3.0e38f, mx1 = -3.0e38f, mx2 = -3.0e38f, mx3 = -3.0e38f;  \
        EPIV(m, 0, lb_0) EPIV(m, 1, lb_1) EPIV(m, 2, lb_2) EPIV(m, 3, lb_3)    \
        EPIRED(m, 0, mx0) EPIRED(m, 1, mx1) EPIRED(m, 2, mx2) EPIRED(m, 3, mx3) }

    EPIMS(0) EPIMS(1) EPIMS(2) EPIMS(3)
    EPIMS(4) EPIMS(5) EPIMS(6) EPIMS(7)
#undef EPIMS
#undef EPIRED
#undef EPIV

    // diagonal blocks: p[a] = 1 - S[a][a], published via atomicExch
    // (device-scope RMW -> coherence point; no fence required).
    if (bx == by && (w_n >> 1) == w_m && (lcol >> 2) == quad) {
        int r = lcol & 3;
        f32x4 d0 = (w_n & 1) ? acc40 : acc00;
        f32x4 d1 = (w_n & 1) ? acc51 : acc11;
        f32x4 d2 = (w_n & 1) ? acc62 : acc22;
        f32x4 d3 = (w_n & 1) ? acc73 : acc33;
        int base = by * 256 + w_m * 128 + ((w_n & 1) << 6) + lcol;
        atomicExch(&p_diag_u[base +  0], __float_as_uint(1.0f - selv(d0, r)));
        atomicExch(&p_diag_u[base + 16], __float_as_uint(1.0f - selv(d1, r)));
        atomicExch(&p_diag_u[base + 32], __float_as_uint(1.0f - selv(d2, r)));
        atomicExch(&p_diag_u[base + 48], __float_as_uint(1.0f - selv(d3, r)));
    }

    // ---------------- fence-free fused finalize (last-block-done) ----------
    // Per-thread: all my atomics ACKed at the coherence point.
    asm volatile("s_waitcnt vmcnt(0)" ::: "memory");
    __syncthreads();   // -> ALL 512 threads' atomics are globally visible
    __shared__ unsigned int sLast;
    if (tid == 0) sLast = (atomicAdd(doneCnt, 1u) == 255u) ? 1u : 0u;
    __syncthreads();
    if (sLast) {
        float sum = 0.0f;
        int cnt = 0;
#pragma unroll
        for (int it = 0; it < 8; ++it) {
            int a = tid + it * 512;
            unsigned int e = atomicOr(&rowmax[a], 0u);          // coherent read
            if (e != 0u) {
                float n = 1.0f - dec_f32(e);
                float pv = __uint_as_float(atomicOr(&p_diag_u[a], 0u));
                float per = pv - n + MARGIN_F;
                if (per > 0.0f) sum += per;
                cnt++;
            }
        }
#pragma unroll
        for (int off = 32; off > 0; off >>= 1) {
            sum += __shfl_xor(sum, off);
            cnt += __shfl_xor(cnt, off);
        }
        __shared__ float sSum[8];
        __shared__ int sCnt[8];
        if (lane == 0) { sSum[w] = sum; sCnt[w] = cnt; }
        __syncthreads();
        if (tid == 0) {
            float ts = 0.0f;
            int tc = 0;
#pragma unroll
            for (int i = 0; i < 8; ++i) { ts += sSum[i]; tc += sCnt[i]; }
            out[0] = (tc > 0) ? ts / (float)tc : 0.0f;
        }
    }
}

extern "C" void kernel_launch(void* const* d_in, const int* in_sizes, int n_in,
                              void* d_out, int out_size, void* d_ws, size_t ws_size,
                              hipStream_t stream) {
    (void)in_sizes; (void)n_in; (void)out_size; (void)ws_size;
    const float* zs = (const float*)d_in[0];
    const float* zi = (const float*)d_in[1];
    const int* labels = (const int*)d_in[2];
    float* out = (float*)d_out;

    char* ws = (char*)d_ws;
    __hip_bfloat16* zb = (__hip_bfloat16*)ws;                       // 8 MB (zs then zi, swizzled)
    unsigned int* rowmax = (unsigned int*)(ws + (8u << 20));        // 16 KB
    unsigned int* p_diag = (unsigned int*)(ws + (8u << 20) + 16384);// 16 KB (float bits)
    unsigned int* doneCnt = (unsigned int*)(ws + (8u << 20) + 32768);

    k_prep<<<2048, 256, 0, stream>>>(zs, zi, zb, rowmax, doneCnt);
    k_gemm_rowmax<<<256, 512, 0, stream>>>(zb, zb + (size_t)NB * ND, labels, rowmax,
                                           p_diag, doneCnt, out);
}

// Round 10
// 97.420 us; speedup vs baseline: 1.0486x; 1.0333x over previous
//
#include <hip/hip_runtime.h>
#include <hip/hip_bf16.h>

typedef __attribute__((ext_vector_type(8))) short bf16x8;
typedef __attribute__((ext_vector_type(4))) float f32x4;

#define NB 4096
#define ND 512
#define MARGIN_F 0.2f

// order-preserving float -> uint encoding for atomicMax.
__device__ __forceinline__ unsigned int enc_f32(float f) {
    unsigned int b = __float_as_uint(f);
    return (b & 0x80000000u) ? ~b : (b | 0x80000000u);
}

__device__ __forceinline__ float dec_f32(unsigned int e) {
    unsigned int b = (e & 0x80000000u) ? (e & 0x7fffffffu) : ~e;
    return __uint_as_float(b);
}

__device__ __forceinline__ void gld_lds16(const void* g, void* l) {
    __builtin_amdgcn_global_load_lds((__attribute__((address_space(1))) void*)g,
                                     (__attribute__((address_space(3))) void*)l,
                                     16, 0, 0);
}

// branchless dynamic element select from f32x4 (constant extracts + cndmask)
__device__ __forceinline__ float selv(f32x4 v, int r) {
    float s01 = (r & 1) ? v[1] : v[0];
    float s23 = (r & 1) ? v[3] : v[2];
    return (r & 2) ? s23 : s01;
}

// ---------------------------------------------------------------------------
// Prep: fp32 -> bf16 fragment-swizzled convert (both matrices), grid 2048.
// Blocks [0,16) additionally zero the 4096-entry rowmax array.
// Layout: chunk (rb16 = row/16, cb = col/32) is 1KB at (rb16*16+cb)*1024;
// within chunk lane L = (row%16) | (((col%32)/8)<<4) holds 8 bf16 at L*16.
// ---------------------------------------------------------------------------
__global__ __launch_bounds__(256) void k_prep(const float* __restrict__ zs,
                                              const float* __restrict__ zi,
                                              __hip_bfloat16* __restrict__ outb,
                                              unsigned int* __restrict__ rowmax) {
    const int bid = blockIdx.x;
    if (bid < 16) rowmax[bid * 256 + threadIdx.x] = 0u;

    int gid = bid * 256 + threadIdx.x;   // [0, 2*4096*64)
    int mat = gid >> 18;                 // 0 = zs, 1 = zi
    int t   = gid & 0x3FFFF;
    int si  = t >> 6;
    int L   = t & 63;
    const float* src = mat ? zi : zs;
    int row = ((si >> 4) << 4) | (L & 15);
    int col = ((si & 15) << 5) | (((L >> 4) & 3) << 3);
    const float4* p = (const float4*)(src + (size_t)row * ND + col);
    float4 f0 = p[0];
    float4 f1 = p[1];
    union { __hip_bfloat16 h[8]; bf16x8 v; } u;
    u.h[0] = __float2bfloat16(f0.x);
    u.h[1] = __float2bfloat16(f0.y);
    u.h[2] = __float2bfloat16(f0.z);
    u.h[3] = __float2bfloat16(f0.w);
    u.h[4] = __float2bfloat16(f1.x);
    u.h[5] = __float2bfloat16(f1.y);
    u.h[6] = __float2bfloat16(f1.z);
    u.h[7] = __float2bfloat16(f1.w);
    bf16x8* dst = (bf16x8*)(outb + ((size_t)mat << 21) + ((size_t)si << 9) + (L << 3));
    *dst = u.v;
}

// ---------------------------------------------------------------------------
// 256x256 tile GEMM (S = Zs . Zi^T), BK=64, 8 waves (2M x 4N), wave tile
// 128x64. Named accumulators (rule #20).
//
// ROUND 10: MINIMAL-SYNC schedule (the one untested macro-structure).
// R3/R4/R6/R7/R8 all used 4-8 barriers per K-tile (m201 phase discipline,
// built for 64-tile steady states) and all tied at 98-102 us total. The
// opposite pole, m97-family: ONE __syncthreads per K-tile (8 barriers vs
// 64), full-tile STAGE at tile top, straight-line 64-MFMA body, compiler-
// scheduled (m97: hipcc's own lgkmcnt interleave is near-optimal; setprio/
// sched_barrier null on 2-phase per m230/m137). ~1300 cyc of compute per
// tile hides the ~500-900 cyc load latency that fine-grained phase waits
// kept exposing.
//
// Ledger: STAGE(kt+1) (8 gld_lds/thread, opposite buffer) issues at tile
// top -- that buffer's reads drained at the previous tile's __syncthreads
// (vmcnt(0)+lgkmcnt(0)+barrier). Tile-end __syncthreads lands T(kt+1) and
// publishes it block-wide. No manual waitcnt anywhere.
// ---------------------------------------------------------------------------
__global__ __launch_bounds__(512, 2) void k_gemm_rowmax(const __hip_bfloat16* __restrict__ zsb,
                                                        const __hip_bfloat16* __restrict__ zib,
                                                        const int* __restrict__ labels,
                                                        unsigned int* __restrict__ rowmax,
                                                        float* __restrict__ p_diag) {
    __shared__ __align__(16) unsigned char lds[131072];
    __shared__ int labA[256];
    __shared__ int labB[256];

    const int tid = threadIdx.x;
    // XCD-aware swizzle: each XCD (bid&7) owns a 4(bx) x 8(by) tile region
    // -> working set 4 B-panels + 8 A-panels = 3 MB < 4 MB per-XCD L2.
    const int bid = blockIdx.x;
    const int xcd = bid & 7, lid = bid >> 3;
    const int bx = ((xcd & 3) << 2) | (lid & 3);
    const int by = ((xcd >> 2) << 3) | (lid >> 2);

    if (tid < 256) labA[tid] = labels[by * 256 + tid];
    else           labB[tid & 255] = labels[bx * 256 + (tid & 255)];

    const char* gA = (const char*)zsb;
    const char* gB = (const char*)zib;
    const int inner = (tid & 127) << 4;        // byte offset within 2KB (rb, kt) strip
    const int aB16 = by * 16 + (tid >> 7);     // staging row-block base (A)
    const int bB16 = bx * 16 + (tid >> 7);     // staging row-block base (B)

    // STAGE(kt, h): 2 x 16B per thread into half-tile slot h of buf[kt&1].
    // h = {0:A-h0, 1:A-h1, 2:B-h0, 3:B-h1}. Same layout as R4 (verified x5).
#define STAGE(kt, h) do {                                                          \
        const char* _g = ((h) & 2) ? gB : gA;                                      \
        int _rb = (((h) & 2) ? bB16 : aB16) + (((h) & 1) << 3);                    \
        unsigned _ld = (((kt) & 1) << 16) + ((h) << 14) + (tid << 4);              \
        gld_lds16(_g + (((size_t)_rb) << 14) + ((kt) << 11) + inner, lds + _ld);   \
        gld_lds16(_g + (((size_t)(_rb + 4)) << 14) + ((kt) << 11) + inner,         \
                  lds + _ld + 8192);                                               \
    } while (0)

    const int w = tid >> 6, lane = tid & 63;
    const int w_m = w >> 2, w_n = w & 3;
    const unsigned fragOff = (unsigned)(lane << 4);
    const unsigned aBase = (unsigned)(w_m << 14) + fragOff;
    const unsigned bBase = 32768u + (unsigned)((w_n >> 1) << 14)
                         + (unsigned)(((w_n & 1) << 2) << 11) + fragOff;

    const f32x4 Z4 = (f32x4){0.f, 0.f, 0.f, 0.f};
    f32x4 acc00=Z4, acc01=Z4, acc02=Z4, acc03=Z4;
    f32x4 acc10=Z4, acc11=Z4, acc12=Z4, acc13=Z4;
    f32x4 acc20=Z4, acc21=Z4, acc22=Z4, acc23=Z4;
    f32x4 acc30=Z4, acc31=Z4, acc32=Z4, acc33=Z4;
    f32x4 acc40=Z4, acc41=Z4, acc42=Z4, acc43=Z4;
    f32x4 acc50=Z4, acc51=Z4, acc52=Z4, acc53=Z4;
    f32x4 acc60=Z4, acc61=Z4, acc62=Z4, acc63=Z4;
    f32x4 acc70=Z4, acc71=Z4, acc72=Z4, acc73=Z4;
    bf16x8 a_0, a_1, a_2, a_3, b_0, b_1, b_2, b_3;

#define MF(A, B, C) __builtin_amdgcn_mfma_f32_16x16x32_bf16((A), (B), (C), 0, 0, 0)
#define LDB(koff)                                                              \
    b_0 = *(const bf16x8*)(lds + par + bBase + (0 << 11) + (koff));            \
    b_1 = *(const bf16x8*)(lds + par + bBase + (1 << 11) + (koff));            \
    b_2 = *(const bf16x8*)(lds + par + bBase + (2 << 11) + (koff));            \
    b_3 = *(const bf16x8*)(lds + par + bBase + (3 << 11) + (koff));
#define LDA(mh, koff)                                                          \
    a_0 = *(const bf16x8*)(lds + par + aBase + ((((mh) << 2) + 0) << 11) + (koff)); \
    a_1 = *(const bf16x8*)(lds + par + aBase + ((((mh) << 2) + 1) << 11) + (koff)); \
    a_2 = *(const bf16x8*)(lds + par + aBase + ((((mh) << 2) + 2) << 11) + (koff)); \
    a_3 = *(const bf16x8*)(lds + par + aBase + ((((mh) << 2) + 3) << 11) + (koff));
#define ROW4(A, R)                                                             \
    acc##R##0 = MF((A), b_0, acc##R##0);                                       \
    acc##R##1 = MF((A), b_1, acc##R##1);                                       \
    acc##R##2 = MF((A), b_2, acc##R##2);                                       \
    acc##R##3 = MF((A), b_3, acc##R##3);

    // prologue: tile 0 fully staged; __syncthreads drains + publishes labs
    STAGE(0, 0); STAGE(0, 1); STAGE(0, 2); STAGE(0, 3);
    __syncthreads();

#pragma unroll
    for (int kt = 0; kt < 8; ++kt) {
        const unsigned par = (unsigned)((kt & 1) << 16);

        // issue next tile's staging first (opposite buffer: free since the
        // previous tile's __syncthreads drained all reads of it)
        if (kt < 7) { STAGE(kt + 1, 0); STAGE(kt + 1, 1); STAGE(kt + 1, 2); STAGE(kt + 1, 3); }

        // straight-line tile body: 24 ds_read_b128 + 64 MFMA, compiler-
        // scheduled (no barriers, no manual waitcnt -- m97 finding).
        LDB(0)
        LDA(0, 0)
        ROW4(a_0, 0) ROW4(a_1, 1) ROW4(a_2, 2) ROW4(a_3, 3)
        LDA(1, 0)
        ROW4(a_0, 4) ROW4(a_1, 5) ROW4(a_2, 6) ROW4(a_3, 7)
        LDB(1024)
        LDA(0, 1024)
        ROW4(a_0, 0) ROW4(a_1, 1) ROW4(a_2, 2) ROW4(a_3, 3)
        LDA(1, 1024)
        ROW4(a_0, 4) ROW4(a_1, 5) ROW4(a_2, 6) ROW4(a_3, 7)

        if (kt < 7) __syncthreads();   // vmcnt(0)+lgkmcnt(0)+barrier: T(kt+1) ready
    }
#undef STAGE
#undef LDA
#undef LDB
#undef ROW4

    // epilogue: C/D layout col = lane&15, row = (lane>>4)*4 + reg
    const int quad = lane >> 4;
    const int lcol = lane & 15;
    const int epiBase = by * 256 + w_m * 128 + quad * 4;

    const int lb_0 = labB[w_n * 64 + 0 * 16 + lcol];
    const int lb_1 = labB[w_n * 64 + 1 * 16 + lcol];
    const int lb_2 = labB[w_n * 64 + 2 * 16 + lcol];
    const int lb_3 = labB[w_n * 64 + 3 * 16 + lcol];

#define EPIV(m, n, LB) {                                                       \
        float v0 = acc##m##n[0], v1 = acc##m##n[1];                            \
        float v2 = acc##m##n[2], v3 = acc##m##n[3];                            \
        if (la0 != (LB) && v0 > mx0) mx0 = v0;                                 \
        if (la1 != (LB) && v1 > mx1) mx1 = v1;                                 \
        if (la2 != (LB) && v2 > mx2) mx2 = v2;                                 \
        if (la3 != (LB) && v3 > mx3) mx3 = v3; }
#define EPIRED(m, r, MX) {                                                     \
        float mm = (MX);                                                       \
        mm = fmaxf(mm, __shfl_xor(mm, 1));                                     \
        mm = fmaxf(mm, __shfl_xor(mm, 2));                                     \
        mm = fmaxf(mm, __shfl_xor(mm, 4));                                     \
        mm = fmaxf(mm, __shfl_xor(mm, 8));                                     \
        if (lcol == 0 && mm > -2.9e38f)                                        \
            atomicMax(&rowmax[epiBase + (m) * 16 + (r)], enc_f32(mm)); }
#define EPIMS(m) {                                                             \
        int la0 = labA[w_m * 128 + (m) * 16 + quad * 4 + 0];                   \
        int la1 = labA[w_m * 128 + (m) * 16 + quad * 4 + 1];                   \
        int la2 = labA[w_m * 128 + (m) * 16 + quad * 4 + 2];                   \
        int la3 = labA[w_m * 128 + (m) * 16 + quad * 4 + 3];                   \
        float mx0 = -3.0e38f, mx1 = -3.0e38f, mx2 = -3.0e38f, mx3 = -3.0e38f;  \
        EPIV(m, 0, lb_0) EPIV(m, 1, lb_1) EPIV(m, 2, lb_2) EPIV(m, 3, lb_3)    \
        EPIRED(m, 0, mx0) EPIRED(m, 1, mx1) EPIRED(m, 2, mx2) EPIRED(m, 3, mx3) }

    EPIMS(0) EPIMS(1) EPIMS(2) EPIMS(3)
    EPIMS(4) EPIMS(5) EPIMS(6) EPIMS(7)
#undef EPIMS
#undef EPIRED
#undef EPIV

    // diagonal blocks: p[a] = 1 - S[a][a]. Wave covers the diagonal iff its
    // 64-col window lies in its 128-row window: (w_n>>1)==w_m. Diag frag
    // pairs are ms = (w_n&1)*4 + ns with frag-row lcol, element r = lcol&3
    // (valid iff quad == lcol>>2). Runtime-ms handled by uniform ternary;
    // runtime-r by branchless constant-extract select (no dynamic indexing).
    if (bx == by && (w_n >> 1) == w_m && (lcol >> 2) == quad) {
        int r = lcol & 3;
        f32x4 d0 = (w_n & 1) ? acc40 : acc00;
        f32x4 d1 = (w_n & 1) ? acc51 : acc11;
        f32x4 d2 = (w_n & 1) ? acc62 : acc22;
        f32x4 d3 = (w_n & 1) ? acc73 : acc33;
        int base = by * 256 + w_m * 128 + ((w_n & 1) << 6) + lcol;
        p_diag[base +  0] = 1.0f - selv(d0, r);
        p_diag[base + 16] = 1.0f - selv(d1, r);
        p_diag[base + 32] = 1.0f - selv(d2, r);
        p_diag[base + 48] = 1.0f - selv(d3, r);
    }
}

// ---------------------------------------------------------------------------
// Finalize: has_neg = (rowmax != 0); n = 1 - dec(rowmax);
// per = relu(p - n + margin); masked mean -> out[0]
// ---------------------------------------------------------------------------
__global__ __launch_bounds__(1024) void k_finalize(const unsigned int* __restrict__ rowmax,
                                                   const float* __restrict__ p_diag,
                                                   float* __restrict__ out) {
    int tid = threadIdx.x;
    float sum = 0.0f;
    int cnt = 0;
#pragma unroll
    for (int it = 0; it < 4; ++it) {
        int a = tid + it * 1024;
        unsigned int e = rowmax[a];
        if (e != 0u) {
            float n = 1.0f - dec_f32(e);
            float per = p_diag[a] - n + MARGIN_F;
            if (per > 0.0f) sum += per;
            cnt++;
        }
    }
#pragma unroll
    for (int off = 32; off > 0; off >>= 1) {
        sum += __shfl_xor(sum, off);
        cnt += __shfl_xor(cnt, off);
    }
    __shared__ float sSum[16];
    __shared__ int sCnt[16];
    int w = tid >> 6, lane = tid & 63;
    if (lane == 0) { sSum[w] = sum; sCnt[w] = cnt; }
    __syncthreads();
    if (tid == 0) {
        float ts = 0.0f;
        int tc = 0;
#pragma unroll
        for (int i = 0; i < 16; ++i) { ts += sSum[i]; tc += sCnt[i]; }
        out[0] = (tc > 0) ? ts / (float)tc : 0.0f;
    }
}

extern "C" void kernel_launch(void* const* d_in, const int* in_sizes, int n_in,
                              void* d_out, int out_size, void* d_ws, size_t ws_size,
                              hipStream_t stream) {
    (void)in_sizes; (void)n_in; (void)out_size; (void)ws_size;
    const float* zs = (const float*)d_in[0];
    const float* zi = (const float*)d_in[1];
    const int* labels = (const int*)d_in[2];
    float* out = (float*)d_out;

    char* ws = (char*)d_ws;
    __hip_bfloat16* zb = (__hip_bfloat16*)ws;                       // 8 MB (zs then zi, swizzled)
    unsigned int* rowmax = (unsigned int*)(ws + (8u << 20));        // 16 KB
    float* p_diag = (float*)(ws + (8u << 20) + 16384);              // 16 KB

    k_prep<<<2048, 256, 0, stream>>>(zs, zi, zb, rowmax);
    k_gemm_rowmax<<<256, 512, 0, stream>>>(zb, zb + (size_t)NB * ND, labels, rowmax, p_diag);
    k_finalize<<<1, 1024, 0, stream>>>(rowmax, p_diag, out);
}